// Round 9
// baseline (197.204 us; speedup 1.0000x reference)
//
#include <hip/hip_runtime.h>
#include <math.h>

#define D       256
#define KCODES  1024
#define NROWS   65536
#define BETA    0.25f
#define MARGIN  1e-3f
#define MAXSURV 7

typedef __attribute__((ext_vector_type(8))) short bf16x8;
typedef __attribute__((ext_vector_type(4))) float f32x4;

__device__ __forceinline__ unsigned int bf16_rne(float f) {
    unsigned int u = __float_as_uint(f);
    return (u + 0x7FFFu + ((u >> 16) & 1u)) >> 16;   // RNE bf16 (inputs are finite/normal)
}
__device__ __forceinline__ f32x4 mfma16(bf16x8 a, bf16x8 b, f32x4 c) {
    return __builtin_amdgcn_mfma_f32_16x16x32_bf16(a, b, c, 0, 0, 0);
}

// ---------- codebook -> bf16 (hi only, RNE): cs[k][0:256]; e2f exact; also zeroes counts
// (folds the former hipMemsetAsync dispatch: 256 blocks x 4 entries = 1024) ----------
__global__ __launch_bounds__(256) void split_cb_kernel(const float* __restrict__ cb,
                                                       ushort* __restrict__ cs,
                                                       float* __restrict__ e2f,
                                                       unsigned int* __restrict__ counts) {
    if (threadIdx.x < 4) counts[blockIdx.x * 4 + threadIdx.x] = 0u;
    int code = blockIdx.x * 4 + (threadIdx.x >> 6);
    int lane = threadIdx.x & 63;
    float4 v = ((const float4*)(cb + (size_t)code * D))[lane];
    double s = (double)v.x * v.x + (double)v.y * v.y +
               (double)v.z * v.z + (double)v.w * v.w;
    ushort* ph = cs + (size_t)code * 256 + lane * 4;
    ph[0] = (ushort)bf16_rne(v.x); ph[1] = (ushort)bf16_rne(v.y);
    ph[2] = (ushort)bf16_rne(v.z); ph[3] = (ushort)bf16_rne(v.w);
    #pragma unroll
    for (int off = 32; off > 0; off >>= 1) s += __shfl_down(s, off, 64);
    if (lane == 0) e2f[code] = (float)s;
}

// ---------- v10: rows=32/wave (2 M-tiles; each B read feeds 2 MFMAs) -> LDS read traffic
// per CU HALVES vs v9. 512-thread blocks (8 waves x 32 rows = 256 rows), grid 256 =
// 1 block/CU. 4-buffer ring, ONE barrier per 2 K-tiles (16+2 barriers vs 32+3):
// iter j computes tiles 2j,2j+1 (bufs (2j)&3,(2j+1)&3), then writes tiles 2j+2,2j+3
// (bufs (2j+2)&3,(2j+3)&3 - disjoint mod 4) and issues loads for 2j+4,2j+5; barrier.
// mrg (256 x 33 u32 = 33,792 B) aliases Bt[0..1] exactly - their last reader is iter 14,
// retired by iter-14's barrier; reused only after the final (iter-15) barrier.
// Per-row math, visit order, packed top-2, merge, tail identical to v9 -> outputs
// bit-identical. ----------
__global__ __launch_bounds__(512) void screen_kernel(
    const float* __restrict__ x, const ushort* __restrict__ cs,
    const float* __restrict__ e2f, const float* __restrict__ cb,
    float* __restrict__ out_idxf, unsigned int* __restrict__ counts,
    float* __restrict__ y, float* __restrict__ msepart)
{
    __shared__ __attribute__((aligned(16))) ushort Bt[4][32 * 264];  // 4 x 16,896 B
    __shared__ float x2s[256];                 // per-local-row exact |x|^2
    unsigned* mrg = (unsigned*)&Bt[0][0];      // 256 x 33 u32, aliases Bt[0..1]
    #define MRG(r, j) mrg[(r) * 33 + (j)]

    const int tid  = threadIdx.x;
    const int wave = tid >> 6, lane = tid & 63;
    const int quad = lane >> 4, m = lane & 15;
    const int rowBase = blockIdx.x * 256;
    const int wrb = rowBase + wave * 32;       // this wave's 32 rows (2 M-tiles)

    const int sc = tid & 31, sp = tid >> 5;    // staging: code 0..31, part 0..15 (16 ushorts)

    // ---- issue loads for tiles 0,1 first: latency hides under the A-fragment build ----
    bf16x8 stg[4];
    {
        const ushort* s0 = cs + (size_t)sc * 256 + sp * 16;          // tile 0
        const ushort* s1 = cs + (size_t)(32 + sc) * 256 + sp * 16;   // tile 1
        stg[0] = *(const bf16x8*)&s0[0];
        stg[1] = *(const bf16x8*)&s0[8];
        stg[2] = *(const bf16x8*)&s1[0];
        stg[3] = *(const bf16x8*)&s1[8];
    }

    // ---- build A fragments (bf16 hi) for 2 M-tiles; accumulate exact x2 ----
    bf16x8 af[2][8];                           // 64 VGPRs
    #pragma unroll
    for (int t = 0; t < 2; ++t) {
        const float* xr = x + (size_t)(wrb + t * 16 + m) * D;
        double s = 0.0;
        #pragma unroll
        for (int c = 0; c < 8; ++c) {
            float4 f0 = *(const float4*)&xr[c * 32 + quad * 8];
            float4 f1 = *(const float4*)&xr[c * 32 + quad * 8 + 4];
            s += (double)f0.x * f0.x + (double)f0.y * f0.y +
                 (double)f0.z * f0.z + (double)f0.w * f0.w;
            s += (double)f1.x * f1.x + (double)f1.y * f1.y +
                 (double)f1.z * f1.z + (double)f1.w * f1.w;
            float ff[8] = {f0.x, f0.y, f0.z, f0.w, f1.x, f1.y, f1.z, f1.w};
            #pragma unroll
            for (int j = 0; j < 8; ++j) af[t][c][j] = (short)bf16_rne(ff[j]);
        }
        s += __shfl_xor(s, 16, 64);
        s += __shfl_xor(s, 32, 64);
        if (quad == 0) x2s[wave * 32 + t * 16 + m] = (float)s;
    }

    // ---- write tiles 0,1; issue loads for tiles 2,3 ----
    {
        ushort* d0 = &Bt[0][sc * 264 + sp * 16];
        ushort* d1 = &Bt[1][sc * 264 + sp * 16];
        *(bf16x8*)&d0[0] = stg[0]; *(bf16x8*)&d0[8] = stg[1];
        *(bf16x8*)&d1[0] = stg[2]; *(bf16x8*)&d1[8] = stg[3];
    }
    {
        const ushort* s2 = cs + (size_t)(64 + sc) * 256 + sp * 16;   // tile 2
        const ushort* s3 = cs + (size_t)(96 + sc) * 256 + sp * 16;   // tile 3
        stg[0] = *(const bf16x8*)&s2[0];
        stg[1] = *(const bf16x8*)&s2[8];
        stg[2] = *(const bf16x8*)&s3[0];
        stg[3] = *(const bf16x8*)&s3[8];
    }

    // ---- packed top-2 per (Mtile,row-reg) over this lane's code class ----
    unsigned u1[2][4], u2[2][4];
    #pragma unroll
    for (int t = 0; t < 2; ++t)
        #pragma unroll
        for (int r = 0; r < 4; ++r) { u1[t][r] = 0xFFFFFFFFu; u2[t][r] = 0xFFFFFFFFu; }

    __syncthreads();                            // tiles 0,1 visible

    // ---- K-loop: 2 tiles/iter, 4-buffer ring, 1 barrier/iter ----
    for (int j = 0; j < 16; ++j) {
        #pragma unroll
        for (int h = 0; h < 2; ++h) {
            const int kt = 2 * j + h;
            const ushort* Bcur = &Bt[kt & 3][0];
            float e2pa = e2f[kt * 32 + m] + 0.5f;        // +0.5 pack bias folded in
            float e2pb = e2f[kt * 32 + 16 + m] + 0.5f;
            #pragma unroll
            for (int nt = 0; nt < 2; ++nt) {
                f32x4 acc0 = {0.f, 0.f, 0.f, 0.f};
                f32x4 acc1 = {0.f, 0.f, 0.f, 0.f};
                const ushort* bp = Bcur + (nt * 16 + m) * 264 + quad * 8;
                __builtin_amdgcn_s_setprio(1);
                #pragma unroll
                for (int c = 0; c < 8; ++c) {
                    bf16x8 bh = *(const bf16x8*)&bp[c * 32];
                    acc0 = mfma16(af[0][c], bh, acc0);   // one B read feeds 2 MFMAs
                    acc1 = mfma16(af[1][c], bh, acc1);
                }
                __builtin_amdgcn_s_setprio(0);
                unsigned kcode = kt * 32 + nt * 16 + m;
                float e2p = nt ? e2pb : e2pa;
                #pragma unroll
                for (int t = 0; t < 2; ++t) {
                    f32x4 acc = t ? acc1 : acc0;
                    #pragma unroll
                    for (int r = 0; r < 4; ++r) {
                        float d = fmaf(-2.f, acc[r], e2p);          // dist + 0.5 (> 0)
                        unsigned u = (__float_as_uint(d) & 0xFFFFFC00u) | kcode;
                        u2[t][r] = min(max(u, u1[t][r]), u2[t][r]); // 3-op network, exact
                        u1[t][r] = min(u, u1[t][r]);                //  (keys distinct)
                    }
                }
            }
        }
        if (j < 15) {
            const int ta = 2 * j + 2, tb = 2 * j + 3;
            ushort* da = &Bt[ta & 3][sc * 264 + sp * 16];
            ushort* db = &Bt[tb & 3][sc * 264 + sp * 16];
            *(bf16x8*)&da[0] = stg[0]; *(bf16x8*)&da[8] = stg[1];
            *(bf16x8*)&db[0] = stg[2]; *(bf16x8*)&db[8] = stg[3];
            if (j < 14) {
                const ushort* sa = cs + (size_t)((ta + 2) * 32 + sc) * 256 + sp * 16;
                const ushort* sb = cs + (size_t)((tb + 2) * 32 + sc) * 256 + sp * 16;
                stg[0] = *(const bf16x8*)&sa[0];
                stg[1] = *(const bf16x8*)&sa[8];
                stg[2] = *(const bf16x8*)&sb[0];
                stg[3] = *(const bf16x8*)&sb[8];
            }
        }
        __syncthreads();
    }

    // ---- per-row merge: 8 waves x 32 rows = 256 rows (mrg aliases Bt[0..1]; safe) ----
    #pragma unroll
    for (int t = 0; t < 2; ++t)
        #pragma unroll
        for (int r = 0; r < 4; ++r) {
            int rowloc = wave * 32 + t * 16 + quad * 4 + r;
            MRG(rowloc, m * 2 + 0) = u1[t][r];
            MRG(rowloc, m * 2 + 1) = u2[t][r];
        }
    __syncthreads();
    if (tid < 256) {
        unsigned umin = 0xFFFFFFFFu;
        #pragma unroll
        for (int jj = 0; jj < 32; ++jj) umin = min(umin, MRG(tid, jj));
        float dfloor = __uint_as_float(umin & 0xFFFFFC00u);
        unsigned limu = (__float_as_uint(dfloor + MARGIN) & 0xFFFFFC00u) | 1023u;
        ushort out[8] = {0, 0, 0, 0, 0, 0, 0, 0};
        int cnt = 0;
        for (int jj = 0; jj < 32; ++jj) {
            unsigned u = MRG(tid, jj);
            if (u <= limu && cnt < MAXSURV) { out[1 + cnt] = (ushort)(u & 1023u); ++cnt; }
        }
        out[0] = (ushort)cnt;
        // park survivors in the first 16 B of this thread's own merge row (reads done)
        *(bf16x8*)&mrg[tid * 33] = *(bf16x8*)out;
    }
    __syncthreads();                            // survivor lists visible to all waves

    // ---- fused rescore/gather tail: each wave finishes its own 32 rows ----
    #pragma unroll 2
    for (int i = 0; i < 32; ++i) {
        int rl  = wave * 32 + i;
        int row = rowBase + rl;
        const ushort* lst = (const ushort*)&mrg[rl * 33];
        int cnt = lst[0];
        float4 xv = ((const float4*)(x + (size_t)row * D))[lane];

        int bk;
        if (cnt == 1) {
            bk = lst[1];                        // fast path: single survivor
        } else {
            float x2 = x2s[rl];
            float bestd = 1e30f;
            int   bestk = 0;
            for (int s = 0; s < cnt; ++s) {
                int k = lst[1 + s];
                float4 cv = ((const float4*)(cb + (size_t)k * D))[lane];
                double p = (double)xv.x * cv.x + (double)xv.y * cv.y +
                           (double)xv.z * cv.z + (double)xv.w * cv.w;
                #pragma unroll
                for (int off = 32; off > 0; off >>= 1) p += __shfl_down(p, off, 64);
                float simf = (float)p;          // correctly-rounded f32 sim (lane 0 exact)
                float tt   = x2 + e2f[k];       // fl32(x2+e2)
                float dq   = tt - 2.0f * simf;  // reference comparator
                if (dq < bestd || (dq == bestd && k < bestk)) { bestd = dq; bestk = k; }
            }
            bk = __shfl(bestk, 0, 64);          // lane 0 had the exact sums
        }
        if (lane == 0) {
            out_idxf[row] = (float)bk;
            atomicAdd(&counts[bk], 1u);         // 1024 distinct addresses -> low contention
        }
        // gather + y + mse partial (identical op order to the old rescore_kernel)
        float4 q = ((const float4*)(cb + (size_t)bk * D))[lane];
        float4 dv;
        dv.x = q.x - xv.x; dv.y = q.y - xv.y; dv.z = q.z - xv.z; dv.w = q.w - xv.w;
        float4 yv;
        yv.x = xv.x + dv.x; yv.y = xv.y + dv.y; yv.z = xv.z + dv.z; yv.w = xv.w + dv.w;
        ((float4*)(y + (size_t)row * D))[lane] = yv;
        float s = dv.x * dv.x + dv.y * dv.y + dv.z * dv.z + dv.w * dv.w;
        #pragma unroll
        for (int off = 32; off > 0; off >>= 1) s += __shfl_down(s, off, 64);
        if (lane == 0) msepart[row] = s;        // plain store, no atomic
    }
    #undef MRG
}

// ---------- final scalars: reduce msepart + counts -> loss, perplexity, usage, H ----------
__global__ __launch_bounds__(1024) void stats_kernel(
    const unsigned int* __restrict__ counts, const float* __restrict__ msepart,
    float* __restrict__ outs)
{
    int t = threadIdx.x;
    // mse partial reduction: 64 coalesced strided reads per thread
    float ms = 0.f;
    #pragma unroll
    for (int j = 0; j < 64; ++j) ms += msepart[t + 1024 * j];

    float p = (float)counts[t] * (1.0f / 65536.0f);
    float h = -p * log2f(p + 1e-10f);
    float u = (p > 0.f) ? 1.f : 0.f;
    #pragma unroll
    for (int off = 32; off > 0; off >>= 1) {
        h  += __shfl_down(h,  off, 64);
        u  += __shfl_down(u,  off, 64);
        ms += __shfl_down(ms, off, 64);
    }
    __shared__ float hs[16], us[16], mss[16];
    int lane = t & 63, w = t >> 6;
    if (lane == 0) { hs[w] = h; us[w] = u; mss[w] = ms; }
    __syncthreads();
    if (t == 0) {
        float H = 0.f, U = 0.f, M = 0.f;
        #pragma unroll
        for (int i = 0; i < 16; ++i) { H += hs[i]; U += us[i]; M += mss[i]; }
        float m = M * (1.0f / 16777216.0f);
        float loss = BETA * m + m;
        float perp = expf(H * 0.69314718055994530942f);
        outs[0] = loss;
        outs[1] = perp;
        outs[2] = U * (1.0f / 1024.0f);
        outs[3] = H;
    }
}

extern "C" void kernel_launch(void* const* d_in, const int* in_sizes, int n_in,
                              void* d_out, int out_size, void* d_ws, size_t ws_size,
                              hipStream_t stream) {
    const float* x  = (const float*)d_in[0];   // [65536, 256]
    const float* cb = (const float*)d_in[1];   // [1024, 256]
    float* out      = (float*)d_out;

    float* y        = out;                      // 16,777,216
    float* out_idxf = out + 16777216;           // 65,536
    float* outs     = out + 16777216 + 65536;   // loss, perp, usage, H

    // ws layout (bytes):
    // [262144  .. 266239]  e2f (1024 f32)
    // [266240  .. 270335]  counts (1024 u32)
    // [1318976 .. 1843263] cs (1024 x 256 ushort, bf16 hi)
    // [1843264 .. 2105407] msepart (65536 f32)
    float*        e2f     = (float*)((char*)d_ws + 262144);
    unsigned int* counts  = (unsigned int*)((char*)d_ws + 266240);
    ushort*       cs      = (ushort*)((char*)d_ws + 1318976);
    float*        msepart = (float*)((char*)d_ws + 1843264);

    split_cb_kernel<<<KCODES / 4, 256, 0, stream>>>(cb, cs, e2f, counts);
    screen_kernel<<<NROWS / 256, 512, 0, stream>>>(x, cs, e2f, cb,
                                                   out_idxf, counts, y, msepart);
    stats_kernel<<<1, 1024, 0, stream>>>(counts, msepart, outs);
}